// Round 9
// baseline (10565.066 us; speedup 1.0000x reference)
//
#include <hip/hip_runtime.h>
#include <stdint.h>

// Embedder: 3-layer shared-weight GRU (B=64,T=2048,H=128) + sigmoid proj.
// v10: fused-tick version of v9. All four pipeline phases (L0,L1,L2,Out) run
// in ONE q-loop per tick: each interface {x,h0,h1,h2} is LDS-read ONCE
// (32 ds_read_b128/wave/tick, the floor; v9 read 56) and each shared weight
// fragment is AGPR-rebuilt ONCE serving 3 layers (28 WFRAGs vs 76; shared
// weights: Bi[g] feeds x/h0/h1, Br[g] feeds h0/h1/h2). 13 independent acc
// chains give the MFMA pipe real ILP. Edge ticks: MFMAs run unguarded
// (zero-init/unused inputs), only state updates + stores are guarded.
// Weights stay pinned in AGPRs (v9's win: kills the reload treadmill).
#define TSEQ 2048
#define HD   128
#define G3   384

typedef __bf16 bf16_t;
typedef __bf16 bf16x8 __attribute__((ext_vector_type(8)));
typedef float  f32x4  __attribute__((ext_vector_type(4)));

union B8 { uint4 u; bf16x8 v; unsigned a4[4]; };

__device__ __forceinline__ float fast_sigmoid(float x) {
    float e = __builtin_amdgcn_exp2f(-1.44269504f * x);
    return __builtin_amdgcn_rcpf(1.0f + e);
}
__device__ __forceinline__ float fast_tanh(float x) {
    x = fminf(9.0f, fmaxf(-9.0f, x));
    float e = __builtin_amdgcn_exp2f(2.88539008f * x);   // exp(2x)
    return 1.0f - 2.0f * __builtin_amdgcn_rcpf(1.0f + e);
}

// AGPR pin: 32-bit, non-tied (the only inline-asm shape clang accepts here).
__device__ __forceinline__ unsigned agpr_w(unsigned v) {
    unsigned d;
    asm("v_accvgpr_write_b32 %0, %1" : "=a"(d) : "v"(v));
    return d;
}

#define MFMA16(A_, B_, C_) (C_) = __builtin_amdgcn_mfma_f32_16x16x32_bf16((A_), (B_), (C_), 0, 0, 0)

// Rebuild one bf16x8 weight fragment from 4 pinned AGPRs. s_nop 2 covers the
// VALU(accvgpr_read)->MFMA RAW hazard the recognizer can't see inside asm.
#define WFRAG(DST, ARR, G, Q)                                               \
  { B8 t_;                                                                  \
    asm("v_accvgpr_read_b32 %0, %4\n\t"                                     \
        "v_accvgpr_read_b32 %1, %5\n\t"                                     \
        "v_accvgpr_read_b32 %2, %6\n\t"                                     \
        "v_accvgpr_read_b32 %3, %7\n\t"                                     \
        "s_nop 2"                                                           \
        : "=v"(t_.a4[0]), "=v"(t_.a4[1]), "=v"(t_.a4[2]), "=v"(t_.a4[3])    \
        : "a"(ARR[G][Q][0]), "a"(ARR[G][Q][1]),                             \
          "a"(ARR[G][Q][2]), "a"(ARR[G][Q][3]));                            \
    DST = t_.v; }

// Tick barrier: LDS visibility only (out-stores / X prefetch stay in flight).
__device__ __forceinline__ void fast_barrier() {
    asm volatile("s_waitcnt lgkmcnt(0)\n\ts_barrier" ::: "memory");
}

// MFMA 16x16x32 bf16 fragment maps (HW-verified layout, carried from v1):
//   A: lane l, elem j -> A[l&15][(l>>4)*8 + j]
//   B: lane l, elem j -> B[(l>>4)*8 + j][l&15]
//   C/D: lane l, reg i -> C[(l>>4)*4 + i][l&15]

// Per-q fused body: read {x,h0,h1,h2} hi/lo once; 7 weight frags; 38 MFMAs.
#define QBODY(Q, PP)                                                        \
  { B8 xh_, xl_, h0h_, h0l_, h1h_, h1l_, h2h_, h2l_;                        \
    { const char* xb = (const char*)&ldsx[PP][0];                           \
      const int base = l15 * 512 + (32 * (Q) + 8 * quad) * 4;               \
      const f32x4 f0 = *(const f32x4*)(xb + (base ^ sw));                   \
      const f32x4 f1 = *(const f32x4*)(xb + ((base + 16) ^ sw));            \
      _Pragma("unroll") for (int j = 0; j < 4; ++j) {                       \
        const bf16_t c0 = (bf16_t)f0[j];                                    \
        xh_.v[j] = c0; xl_.v[j] = (bf16_t)(f0[j] - (float)c0);              \
        const bf16_t c1 = (bf16_t)f1[j];                                    \
        xh_.v[j + 4] = c1; xl_.v[j + 4] = (bf16_t)(f1[j] - (float)c1);      \
      } }                                                                   \
    h0h_.u = ldsh[0][(PP) ^ 1][0][Q][lane];                                 \
    h0l_.u = ldsh[0][(PP) ^ 1][1][Q][lane];                                 \
    h1h_.u = ldsh[1][(PP) ^ 1][0][Q][lane];                                 \
    h1l_.u = ldsh[1][(PP) ^ 1][1][Q][lane];                                 \
    h2h_.u = ldsh[2][(PP) ^ 1][0][Q][lane];                                 \
    h2l_.u = ldsh[2][(PP) ^ 1][1][Q][lane];                                 \
    bf16x8 wf;                                                              \
    WFRAG(wf, BiA, 0, Q)                                                    \
    MFMA16(xh_.v,  wf, aZ0); MFMA16(xl_.v,  wf, aZ0);                       \
    MFMA16(h0h_.v, wf, aZ1); MFMA16(h0l_.v, wf, aZ1);                       \
    MFMA16(h1h_.v, wf, aZ2); MFMA16(h1l_.v, wf, aZ2);                       \
    WFRAG(wf, BiA, 1, Q)                                                    \
    MFMA16(xh_.v,  wf, aR0); MFMA16(xl_.v,  wf, aR0);                       \
    MFMA16(h0h_.v, wf, aR1); MFMA16(h0l_.v, wf, aR1);                       \
    MFMA16(h1h_.v, wf, aR2); MFMA16(h1l_.v, wf, aR2);                       \
    WFRAG(wf, BiA, 2, Q)                                                    \
    MFMA16(xh_.v,  wf, aX0); MFMA16(xl_.v,  wf, aX0);                       \
    MFMA16(h0h_.v, wf, aX1); MFMA16(h0l_.v, wf, aX1);                       \
    MFMA16(h1h_.v, wf, aX2); MFMA16(h1l_.v, wf, aX2);                       \
    WFRAG(wf, BrA, 0, Q)                                                    \
    MFMA16(h0h_.v, wf, aZ0); MFMA16(h0l_.v, wf, aZ0);                       \
    MFMA16(h1h_.v, wf, aZ1); MFMA16(h1l_.v, wf, aZ1);                       \
    MFMA16(h2h_.v, wf, aZ2); MFMA16(h2l_.v, wf, aZ2);                       \
    WFRAG(wf, BrA, 1, Q)                                                    \
    MFMA16(h0h_.v, wf, aR0); MFMA16(h0l_.v, wf, aR0);                       \
    MFMA16(h1h_.v, wf, aR1); MFMA16(h1l_.v, wf, aR1);                       \
    MFMA16(h2h_.v, wf, aR2); MFMA16(h2l_.v, wf, aR2);                       \
    WFRAG(wf, BrA, 2, Q)                                                    \
    MFMA16(h0h_.v, wf, aH0); MFMA16(h0l_.v, wf, aH0);                       \
    MFMA16(h1h_.v, wf, aH1); MFMA16(h1l_.v, wf, aH1);                       \
    MFMA16(h2h_.v, wf, aH2); MFMA16(h2l_.v, wf, aH2);                       \
    WFRAG(wf, BwA, 0, Q)                                                    \
    MFMA16(h2h_.v, wf, aO);  MFMA16(h2l_.v, wf, aO);                        \
  }

// GRU elementwise + h-state update + LDS h write for one layer.
#define EWRITE(AZ, AR, AX, AH, HP, IF, PP)                                  \
  _Pragma("unroll") for (int i = 0; i < 4; ++i) {                           \
    const float zg = fast_sigmoid(AZ[i]);                                   \
    const float rg = fast_sigmoid(AR[i]);                                   \
    const float cd = fast_tanh(AX[i] + rg * AH[i]);                         \
    const float hn = cd + zg * (HP[i] - cd);                                \
    HP[i] = hn;                                                             \
    const bf16_t hh = (bf16_t)hn;                                           \
    const bf16_t hl = (bf16_t)(hn - (float)hh);                             \
    const int mrow = 4 * quad + i;                                          \
    ((bf16_t*)&ldsh[IF][PP][0][qq][lamb + mrow])[jj] = hh;                  \
    ((bf16_t*)&ldsh[IF][PP][1][qq][lamb + mrow])[jj] = hl;                  \
  }

// One fused tick: all reads from parity PP^1, all writes to parity PP.
// X(TT+1) register-staged early, LDS-written late (T14).
#define TICK(TT, PP)                                                          \
  {                                                                           \
    uint4 xstage;                                                             \
    const bool do_stage = ((TT) + 1 < TSEQ);                                  \
    if (do_stage) xstage = *(const uint4*)(xsrc0 + (size_t)((TT) + 1) * HD);  \
    f32x4 aZ0 = {bZ, bZ, bZ, bZ},     aZ1 = aZ0, aZ2 = aZ0;                   \
    f32x4 aR0 = {bR, bR, bR, bR},     aR1 = aR0, aR2 = aR0;                   \
    f32x4 aX0 = {bXC, bXC, bXC, bXC}, aX1 = aX0, aX2 = aX0;                   \
    f32x4 aH0 = {bHC, bHC, bHC, bHC}, aH1 = aH0, aH2 = aH0;                   \
    f32x4 aO  = {bb, bb, bb, bb};                                             \
    QBODY(0, PP) QBODY(1, PP) QBODY(2, PP) QBODY(3, PP)                       \
    if ((TT) < TSEQ)                    { EWRITE(aZ0, aR0, aX0, aH0, hp0, 0, PP) } \
    if ((TT) >= 1 && (TT) < TSEQ + 1)   { EWRITE(aZ1, aR1, aX1, aH1, hp1, 1, PP) } \
    if ((TT) >= 2 && (TT) < TSEQ + 2)   { EWRITE(aZ2, aR2, aX2, aH2, hp2, 2, PP) } \
    if ((TT) >= 3 && (TT) < TSEQ + 3) {                                       \
      const int t3 = (TT) - 3;                                                \
      _Pragma("unroll") for (int i = 0; i < 4; ++i)                           \
        out[((size_t)(16 * b + 4 * quad + i) * TSEQ + t3) * HD + cc] =        \
            fast_sigmoid(aO[i]);                                              \
    }                                                                         \
    if (do_stage) *(uint4*)((char*)&ldsx[(PP) ^ 1][0] + tid * 16) = xstage;   \
    fast_barrier();                                                           \
  }

__global__ __attribute__((amdgpu_flat_work_group_size(512, 512),
                          amdgpu_waves_per_eu(2, 2))) void fused_gru(
    const float* __restrict__ X,
    const float* __restrict__ Wk, const float* __restrict__ Wr,
    const float* __restrict__ bi, const float* __restrict__ br,
    const float* __restrict__ Wo, const float* __restrict__ bo,
    float* __restrict__ out)
{
    // h exchange buffers: [iface][parity][hi/lo][q][lane], A-frag packed. 48 KB
    __shared__ uint4 ldsh[3][2][2][4][64];
    // X tile, fp32, XOR-swizzled (source-swizzled write, XOR read). 16 KB
    __shared__ float ldsx[2][16 * HD];

    const int b    = blockIdx.x;             // batch quarter (16 rows)
    const int tid  = threadIdx.x;
    const int w    = tid >> 6;
    const int lane = tid & 63;
    const int l15  = lane & 15;
    const int quad = lane >> 4;
    const int sw   = (l15 & 7) << 4;

    // Weight fragments: fp32 load + bf16 convert ONCE, pinned into AGPRs as
    // 4x u32 each (opaque asm defs -> cannot be sunk/remat'd; resident for
    // all 2052 ticks). 112 AGPRs + 128 arch VGPRs = 240 <= 256 @ 2 waves/EU.
    unsigned BiA[3][4][4], BrA[3][4][4], BwA[1][4][4];
#pragma unroll
    for (int g = 0; g < 3; ++g)
#pragma unroll
        for (int q = 0; q < 4; ++q) {
            const int col = 128 * g + 16 * w + l15;
            B8 tr, ti;
#pragma unroll
            for (int j = 0; j < 8; ++j) {
                const int row = 32 * q + 8 * quad + j;
                tr.v[j] = (bf16_t)Wr[row * G3 + col];
                ti.v[j] = (bf16_t)Wk[row * G3 + col];
            }
#pragma unroll
            for (int k = 0; k < 4; ++k) {
                BrA[g][q][k] = agpr_w(tr.a4[k]);
                BiA[g][q][k] = agpr_w(ti.a4[k]);
            }
        }
#pragma unroll
    for (int q = 0; q < 4; ++q) {
        B8 tw;
#pragma unroll
        for (int j = 0; j < 8; ++j)
            tw.v[j] = (bf16_t)Wo[(32 * q + 8 * quad + j) * HD + 16 * w + l15];
#pragma unroll
        for (int k = 0; k < 4; ++k) BwA[0][q][k] = agpr_w(tw.a4[k]);
    }

    const int   cc  = 16 * w + l15;
    const float bZ  = bi[cc] + br[cc];
    const float bR  = bi[128 + cc] + br[128 + cc];
    const float bXC = bi[256 + cc];
    const float bHC = br[256 + cc];
    const float bb  = bo[cc];

    // LDS h-write mapping: A[mrow][cc] -> frag q=cc>>5, lane=mrow+16*((cc>>3)&3), elem cc&7
    const int qq   = cc >> 5;
    const int lamb = 16 * ((cc >> 3) & 3);
    const int jj   = cc & 7;

    {   // zero all h buffers: h(-1) = 0 for every layer, both parities
        uint4 z4; z4.x = z4.y = z4.z = z4.w = 0u;
        for (int i = tid; i < 3 * 2 * 2 * 4 * 64; i += 512) ((uint4*)ldsh)[i] = z4;
    }

    // X staging: thread tid -> row=tid>>5, linear LDS dest tid*16; SOURCE
    // 16B-group XOR-swizzled so the read-side XOR lands conflict-free.
    const int xrow = tid >> 5;
    const int xcg  = (tid & 31) ^ (xrow & 7);
    const float* xsrc0 = X + (size_t)(16 * b + xrow) * TSEQ * HD + 4 * xcg;

    {   // prologue: stage X(t=0) into parity 0
        const uint4 x0 = *(const uint4*)xsrc0;
        *(uint4*)((char*)&ldsx[0][0] + tid * 16) = x0;
    }
    __syncthreads();

    float hp0[4] = {0.f, 0.f, 0.f, 0.f};
    float hp1[4] = {0.f, 0.f, 0.f, 0.f};
    float hp2[4] = {0.f, 0.f, 0.f, 0.f};

    // 2051 real ticks (+1 dead pad tick so the 2x parity unroll stays literal)
    for (int tau = 0; tau < TSEQ + 4; tau += 2) {
        TICK(tau, 0)
        TICK(tau + 1, 1)
    }
}

extern "C" void kernel_launch(void* const* d_in, const int* in_sizes, int n_in,
                              void* d_out, int out_size, void* d_ws, size_t ws_size,
                              hipStream_t stream) {
    const float* X  = (const float*)d_in[0];
    const float* Wk = (const float*)d_in[1];
    const float* Wr = (const float*)d_in[2];
    const float* bi = (const float*)d_in[3];
    const float* br = (const float*)d_in[4];
    const float* Wo = (const float*)d_in[5];
    const float* bo = (const float*)d_in[6];
    float* out = (float*)d_out;
    (void)d_ws; (void)ws_size;  // no workspace: no rings, no flags

    fused_gru<<<4, 512, 0, stream>>>(X, Wk, Wr, bi, br, Wo, bo, out);
}